// Round 14
// baseline (351.786 us; speedup 1.0000x reference)
//
#include <hip/hip_runtime.h>
#include <hip/hip_bf16.h>

// GAT_52673478918844 — 2-layer GAT, N=100k, E=1.6M.
// CSR-gather + MFMA GEMMs + fully-bucketed CSR build (no global atomics)
// + 8-col/lane gather waves, 8-edge unroll, zero-copy h/feat2 overlays.
//
// ws layout (gate 46.1 MB):
//   +0        flag (int, padded to 256B)
//   +256      hC : N x 128 bf16 (25.6 MB)
//             phase 1: feat1 (all 128 cols)
//             phase 2: cols 0-63 slots = h-hi (written in-place by agg1 half-1)
//                      cols 64-127 slots = feat2 (written by gemm2)
//   +25.6M    T  : N x 64 bf16 (12.8 MB): pair_buf during CSR build, then h-lo
//   +38.4M    csr: int E — src ids sorted by dst                      6.4 MB
//   +44.8M    ptr: int N — row ends (gcnt overlays during build)      0.4 MB
//   +45.2M    el2, er2 (f32 N each)                                   0.8 MB
//   +46.0M    total[98], bstart[99] scratch                           ~4 KB
//   +46.004M  W1T bf16 128x128 (32 KB), W2T bf16 64x128 (16 KB)
// el1/er1 (f32 N*8 each) live in d_out until layer-1 agg done.

#define NN 100000
#define NE 1600000
#define NB 391          // ceil(NE/4096) edge blocks
#define NBK 98          // buckets = ceil(NN/1024), bucket = dst >> 10

typedef unsigned short u16;
typedef unsigned int   u32;
typedef __attribute__((ext_vector_type(4))) float f32x4;
typedef __attribute__((ext_vector_type(8))) short short8;   // 8 bf16 bits

__device__ __forceinline__ float bf2f(u16 u) { return __uint_as_float(((u32)u) << 16); }
__device__ __forceinline__ float bflo(u32 u) { return __uint_as_float(u << 16); }
__device__ __forceinline__ float bfhi(u32 u) { return __uint_as_float(u & 0xffff0000u); }
__device__ __forceinline__ u16 f2bf(float f) {
    u32 u = __float_as_uint(f);
    return (u16)((u + 0x7fffu + ((u >> 16) & 1u)) >> 16);   // RNE
}
__device__ __forceinline__ float lrelu(float v) { return v > 0.f ? v : 0.2f * v; }
__device__ __forceinline__ float loadf(const void* p, size_t i, int isf32) {
    return isf32 ? ((const float*)p)[i] : bf2f(((const u16*)p)[i]);
}

// ---- dtype autodetect ----
__global__ void k_detect(const u16* __restrict__ x, int* __restrict__ flag)
{
    __shared__ float s[256];
    int t = threadIdx.x;
    float a = 0.f;
    for (int i = t; i < 1024; i += 256) a += fminf(fabsf(bf2f(x[i])), 1e6f);
    s[t] = a;
    __syncthreads();
    if (t == 0) {
        float tot = 0.f;
        for (int i = 0; i < 256; ++i) tot += s[i];
        *flag = (tot * (1.f / 1024.f) > 100.f) ? 1 : 0;
    }
}

// ---- beacon ----
__global__ void k_beacon(u16* __restrict__ out, int n, float code)
{
    int tid = blockIdx.x * 256 + threadIdx.x;
    if (tid < n) out[tid] = f2bf(code);
}

// ---- weight transpose + bf16 convert: W1T[n][k], W2T[n][k] ----
__global__ __launch_bounds__(256) void k_prep(
    const void* __restrict__ W1, const void* __restrict__ W2,
    const int* __restrict__ flag, u16* __restrict__ W1T, u16* __restrict__ W2T)
{
    int i = blockIdx.x * 256 + threadIdx.x;
    int isf32 = *flag;
    if (i < 16384) {
        int k = i >> 7, n = i & 127;
        W1T[n * 128 + k] = isf32 ? f2bf(((const float*)W1)[i]) : ((const u16*)W1)[i];
    } else if (i < 24576) {
        int j = i - 16384;
        int k = j >> 6, n = j & 63;
        W2T[n * 128 + k] = isf32 ? f2bf(((const float*)W2)[j]) : ((const u16*)W2)[j];
    }
}

// ---- GEMM1 (MFMA): feat1 = x @ W1 -> hC (bf16) + el1/er1 (f32) ----
__global__ __launch_bounds__(256) void k_gemm1m(
    const void* __restrict__ x, const u16* __restrict__ W1T,
    const void* __restrict__ al1, const void* __restrict__ ar1,
    const int* __restrict__ flag,
    u16* __restrict__ hC, float* __restrict__ el1, float* __restrict__ er1)
{
    __shared__ __align__(16) char smem[52224];
    __shared__ float alS[128], arS[128];
    u16* xT = (u16*)smem;              // [64][136]
    u16* wT = (u16*)(smem + 17408);    // [128][136]
    float* fB = (float*)smem;          // [64][132] f32, epilogue reuse

    const int t  = threadIdx.x;
    const int r0 = blockIdx.x * 64;
    const int isf32 = *flag;

    if (t < 128) { alS[t] = loadf(al1, t, isf32); arS[t] = loadf(ar1, t, isf32); }

    {
        const uint4* wg = (const uint4*)W1T;
        #pragma unroll
        for (int it = 0; it < 8; ++it) {
            int idx = t + it * 256;
            int r = idx >> 4, k = (idx & 15) * 8;
            *(uint4*)&wT[r * 136 + k] = wg[idx];
        }
    }
    if (!isf32) {
        const u16* xg = (const u16*)x;
        #pragma unroll
        for (int it = 0; it < 4; ++it) {
            int idx = t + it * 256;
            int r = idx >> 4, k = (idx & 15) * 8;
            int rr = r0 + r; if (rr >= NN) rr = NN - 1;
            *(uint4*)&xT[r * 136 + k] = *(const uint4*)&xg[(size_t)rr * 128 + k];
        }
    } else {
        const float* xg = (const float*)x;
        #pragma unroll
        for (int it = 0; it < 8; ++it) {
            int idx = t + it * 256;
            int r = idx >> 5, k = (idx & 31) * 4;
            int rr = r0 + r; if (rr >= NN) rr = NN - 1;
            float4 v = *(const float4*)&xg[(size_t)rr * 128 + k];
            ushort4 o; o.x = f2bf(v.x); o.y = f2bf(v.y); o.z = f2bf(v.z); o.w = f2bf(v.w);
            *(ushort4*)&xT[r * 136 + k] = o;
        }
    }
    __syncthreads();

    const int w = t >> 6, lane = t & 63;
    const int lm = lane & 15, lk = (lane >> 4) * 8;
    const u16* aP = &xT[(w * 16 + lm) * 136 + lk];
    const u16* bP = &wT[lm * 136 + lk];

    f32x4 acc[8];
    #pragma unroll
    for (int i = 0; i < 8; ++i) acc[i] = (f32x4){0.f, 0.f, 0.f, 0.f};

    #pragma unroll
    for (int ks = 0; ks < 4; ++ks) {
        short8 a = *(const short8*)(aP + ks * 32);
        #pragma unroll
        for (int ct = 0; ct < 8; ++ct) {
            short8 b = *(const short8*)(bP + ct * 16 * 136 + ks * 32);
            acc[ct] = __builtin_amdgcn_mfma_f32_16x16x32_bf16(a, b, acc[ct], 0, 0, 0);
        }
    }
    __syncthreads();

    {
        int rbase = w * 16 + (lane >> 4) * 4;
        #pragma unroll
        for (int ct = 0; ct < 8; ++ct) {
            #pragma unroll
            for (int r = 0; r < 4; ++r)
                fB[(rbase + r) * 132 + ct * 16 + lm] = acc[ct][r];
        }
    }
    __syncthreads();

    #pragma unroll
    for (int it = 0; it < 16; ++it) {
        int idx = t + it * 256;                    // < 4096
        int r = idx >> 6, c2 = (idx & 63) * 2;
        int rr = r0 + r;
        if (rr < NN) {
            u32 pk = (u32)f2bf(fB[r * 132 + c2]) | ((u32)f2bf(fB[r * 132 + c2 + 1]) << 16);
            *(u32*)&hC[(size_t)rr * 128 + c2] = pk;
        }
    }
    #pragma unroll
    for (int p = 0; p < 2; ++p) {
        int task = t + p * 256;                    // < 512
        int r = task >> 3, hh = task & 7;
        float el = 0.f, er = 0.f;
        #pragma unroll
        for (int dd = 0; dd < 16; ++dd) {
            float f = fB[r * 132 + hh * 16 + dd];
            el += f * alS[hh * 16 + dd];
            er += f * arS[hh * 16 + dd];
        }
        int rr = r0 + r;
        if (rr < NN) { el1[rr * 8 + hh] = el; er1[rr * 8 + hh] = er; }
    }
}

// ---- GEMM2 (MFMA): feat2 = h @ W2 -> feat2 (hC cols 64-127 slots) + el2/er2 ----
// h read from T (cols 0-63, stride 64) and hC cols 0-63 slots (cols 64-127, stride 128)
__global__ __launch_bounds__(256) void k_gemm2m(
    const u16* __restrict__ hT, const u16* __restrict__ hHi,
    const u16* __restrict__ W2T,
    const void* __restrict__ al2, const void* __restrict__ ar2,
    const int* __restrict__ flag,
    u16* __restrict__ feat2, float* __restrict__ el2, float* __restrict__ er2)
{
    __shared__ __align__(16) char smem[34816];
    __shared__ float alS[64], arS[64];
    u16* xT = (u16*)smem;              // [64][136]
    u16* wT = (u16*)(smem + 17408);    // [64][136]
    float* fB = (float*)smem;          // [64][68] f32, epilogue reuse

    const int t  = threadIdx.x;
    const int r0 = blockIdx.x * 64;
    const int isf32 = *flag;

    if (t < 64) { alS[t] = loadf(al2, t, isf32); arS[t] = loadf(ar2, t, isf32); }

    {
        const uint4* wg = (const uint4*)W2T;       // 64*128 = 1024 uint4
        #pragma unroll
        for (int it = 0; it < 4; ++it) {
            int idx = t + it * 256;
            int r = idx >> 4, k = (idx & 15) * 8;
            *(uint4*)&wT[r * 136 + k] = wg[idx];
        }
    }
    #pragma unroll
    for (int it = 0; it < 4; ++it) {
        int idx = t + it * 256;
        int r = idx >> 4, j = idx & 15;            // 16-B chunk = 8 cols
        int rr = r0 + r; if (rr >= NN) rr = NN - 1;
        const u16* sp = (j < 8) ? &hT[(size_t)rr * 64 + j * 8]
                                : &hHi[(size_t)rr * 128 + (j - 8) * 8];
        *(uint4*)&xT[r * 136 + j * 8] = *(const uint4*)sp;
    }
    __syncthreads();

    const int w = t >> 6, lane = t & 63;
    const int lm = lane & 15, lk = (lane >> 4) * 8;
    const u16* aP = &xT[(w * 16 + lm) * 136 + lk];
    const u16* bP = &wT[lm * 136 + lk];

    f32x4 acc[4];
    #pragma unroll
    for (int i = 0; i < 4; ++i) acc[i] = (f32x4){0.f, 0.f, 0.f, 0.f};

    #pragma unroll
    for (int ks = 0; ks < 4; ++ks) {
        short8 a = *(const short8*)(aP + ks * 32);
        #pragma unroll
        for (int ct = 0; ct < 4; ++ct) {
            short8 b = *(const short8*)(bP + ct * 16 * 136 + ks * 32);
            acc[ct] = __builtin_amdgcn_mfma_f32_16x16x32_bf16(a, b, acc[ct], 0, 0, 0);
        }
    }
    __syncthreads();

    {
        int rbase = w * 16 + (lane >> 4) * 4;
        #pragma unroll
        for (int ct = 0; ct < 4; ++ct) {
            #pragma unroll
            for (int r = 0; r < 4; ++r)
                fB[(rbase + r) * 68 + ct * 16 + lm] = acc[ct][r];
        }
    }
    __syncthreads();

    // feat2 store into hC cols 64-127 slots: stride 128, cols 0-63 local
    #pragma unroll
    for (int it = 0; it < 8; ++it) {
        int idx = t + it * 256;                    // < 2048
        int r = idx >> 5, c2 = (idx & 31) * 2;
        int rr = r0 + r;
        if (rr < NN) {
            u32 pk = (u32)f2bf(fB[r * 68 + c2]) | ((u32)f2bf(fB[r * 68 + c2 + 1]) << 16);
            *(u32*)&feat2[(size_t)rr * 128 + c2] = pk;
        }
    }
    {
        int r = t >> 2, q = t & 3;
        float el = 0.f, er = 0.f;
        #pragma unroll
        for (int dd = 0; dd < 16; ++dd) {
            float f = fB[r * 68 + q * 16 + dd];
            el += f * alS[q * 16 + dd];
            er += f * arS[q * 16 + dd];
        }
        el += __shfl_xor(el, 1); el += __shfl_xor(el, 2);
        er += __shfl_xor(er, 1); er += __shfl_xor(er, 2);
        int rr = r0 + r;
        if (q == 0 && rr < NN) { el2[rr] = el; er2[rr] = er; }
    }
}

// ---- CSR build (fully bucketed, no global atomics, packed u32 pairs) ----
// pack = (local_dst << 17) | src   (src < 2^17, local_dst < 1024)

__global__ __launch_bounds__(256) void k_cnt(
    const int* __restrict__ dst, int* __restrict__ gcnt)
{
    __shared__ int cnt[NBK];
    const int t = threadIdx.x;
    if (t < NBK) cnt[t] = 0;
    __syncthreads();
    const int e0 = blockIdx.x * 4096 + t;
    #pragma unroll
    for (int i = 0; i < 16; ++i) {
        int e = e0 + i * 256;
        if (e < NE) atomicAdd(&cnt[dst[e] >> 10], 1);
    }
    __syncthreads();
    if (t < NBK) gcnt[blockIdx.x * NBK + t] = cnt[t];
}

__global__ __launch_bounds__(512) void k_scan1(
    int* __restrict__ gcnt, int* __restrict__ total)
{
    __shared__ int s[512];
    const int t = threadIdx.x, k = blockIdx.x;
    int c = (t < NB) ? gcnt[t * NBK + k] : 0;
    s[t] = c; __syncthreads();
    for (int off = 1; off < 512; off <<= 1) {
        int v = (t >= off) ? s[t - off] : 0;
        __syncthreads();
        s[t] += v;
        __syncthreads();
    }
    if (t < NB) gcnt[t * NBK + k] = s[t] - c;
    if (t == NB - 1) total[k] = s[t];
}

__global__ __launch_bounds__(128) void k_scan2(
    const int* __restrict__ total, int* __restrict__ bstart)
{
    __shared__ int s[128];
    const int t = threadIdx.x;
    int c = (t < NBK) ? total[t] : 0;
    s[t] = c; __syncthreads();
    for (int off = 1; off < 128; off <<= 1) {
        int v = (t >= off) ? s[t - off] : 0;
        __syncthreads();
        s[t] += v;
        __syncthreads();
    }
    if (t < NBK) bstart[t] = s[t] - c;
    if (t == NBK - 1) bstart[NBK] = s[t];
}

__global__ __launch_bounds__(256) void k_part(
    const int* __restrict__ src, const int* __restrict__ dst,
    const int* __restrict__ gcnt, const int* __restrict__ bstart,
    u32* __restrict__ pair)
{
    __shared__ int cnt[NBK];
    __shared__ int gb[NBK];
    const int t = threadIdx.x;
    const int e0 = blockIdx.x * 4096 + t;

    if (t < NBK) cnt[t] = 0;
    __syncthreads();

    int sv[16], dv[16], rk[16];
    #pragma unroll
    for (int i = 0; i < 16; ++i) {
        int e = e0 + i * 256;
        if (e < NE) {
            sv[i] = src[e];
            dv[i] = dst[e];
            rk[i] = atomicAdd(&cnt[dv[i] >> 10], 1);
        }
    }
    __syncthreads();
    if (t < NBK) gb[t] = bstart[t] + gcnt[blockIdx.x * NBK + t];
    __syncthreads();

    #pragma unroll
    for (int i = 0; i < 16; ++i) {
        int e = e0 + i * 256;
        if (e < NE) {
            u32 p = ((u32)(dv[i] & 1023) << 17) | (u32)sv[i];
            pair[gb[dv[i] >> 10] + rk[i]] = p;
        }
    }
}

__global__ __launch_bounds__(256) void k_build(
    const u32* __restrict__ pair, const int* __restrict__ bstart,
    int* __restrict__ ptr, int* __restrict__ csr_src)
{
    __shared__ int cur[1024];
    __shared__ int part[256];
    const int t = threadIdx.x;
    const int b = blockIdx.x;
    const int r0 = b << 10;
    const int nloc = min(1024, NN - r0);
    const int bs = bstart[b], be = bstart[b + 1];

    for (int i = t; i < 1024; i += 256) cur[i] = 0;
    __syncthreads();

    for (int e = bs + t; e < be; e += 256)
        atomicAdd(&cur[pair[e] >> 17], 1);
    __syncthreads();

    int t4 = t * 4;
    int c0 = cur[t4], c1 = cur[t4 + 1], c2 = cur[t4 + 2], c3 = cur[t4 + 3];
    int sum = c0 + c1 + c2 + c3;
    part[t] = sum; __syncthreads();
    for (int off = 1; off < 256; off <<= 1) {
        int v = (t >= off) ? part[t - off] : 0;
        __syncthreads();
        part[t] += v;
        __syncthreads();
    }
    int basep = bs + part[t] - sum;
    cur[t4]     = basep;
    cur[t4 + 1] = basep + c0;
    cur[t4 + 2] = basep + c0 + c1;
    cur[t4 + 3] = basep + c0 + c1 + c2;
    __syncthreads();

    for (int e = bs + t; e < be; e += 256) {
        u32 p = pair[e];
        int pos = atomicAdd(&cur[p >> 17], 1);
        csr_src[pos] = (int)(p & 0x1FFFFu);
    }
    __syncthreads();

    for (int i = t; i < nloc; i += 256) ptr[r0 + i] = cur[i];   // row ends
}

// ---- edge-accumulate helper (order-preserving) ----
#define ACC_EDGE(ww, ff)                                         \
    a0 += (ww) * bflo((ff).x); a1 += (ww) * bfhi((ff).x);        \
    a2 += (ww) * bflo((ff).y); a3 += (ww) * bfhi((ff).y);        \
    a4 += (ww) * bflo((ff).z); a5 += (ww) * bfhi((ff).z);        \
    a6 += (ww) * bflo((ff).w); a7 += (ww) * bfhi((ff).w);        \
    wsum += (ww);

// ---- layer-1 aggregation: 8 nodes/wave, 8 lanes/node, 8 cols/lane,
//      8-edge + 4-edge + singles (order-preserving); output stride param ----
__global__ __launch_bounds__(256) void k_agg1c(
    const int* __restrict__ ptr, const int* __restrict__ csr_src,
    const float* __restrict__ el1, const float* __restrict__ er1,
    const u16* __restrict__ feat1,
    const void* __restrict__ b1, const int* __restrict__ flag,
    u16* __restrict__ outp, int ostride, int cb)
{
    const int wv = threadIdx.x >> 6, lane = threadIdx.x & 63;
    const int g = lane >> 3, ql = lane & 7;
    const int d = blockIdx.x * 32 + wv * 8 + g;      // 3125 * 32 = NN exactly
    const int c0 = cb + ql * 8;                      // 8 cols: c0..c0+7
    const int hh = c0 >> 4;

    float er_d = er1[d * 8 + hh];
    int start = d ? ptr[d - 1] : 0;
    int end   = ptr[d];

    float a0 = 0.f, a1 = 0.f, a2 = 0.f, a3 = 0.f;
    float a4 = 0.f, a5 = 0.f, a6 = 0.f, a7 = 0.f, wsum = 0.f;
    int i = start;
    while (i + 8 <= end) {
        int s0 = csr_src[i],     s1 = csr_src[i + 1];
        int s2 = csr_src[i + 2], s3 = csr_src[i + 3];
        int s4 = csr_src[i + 4], s5 = csr_src[i + 5];
        int s6 = csr_src[i + 6], s7 = csr_src[i + 7];
        float e0 = el1[s0 * 8 + hh], e1 = el1[s1 * 8 + hh];
        float e2 = el1[s2 * 8 + hh], e3 = el1[s3 * 8 + hh];
        float e4 = el1[s4 * 8 + hh], e5 = el1[s5 * 8 + hh];
        float e6 = el1[s6 * 8 + hh], e7 = el1[s7 * 8 + hh];
        uint4 f0 = *(const uint4*)&feat1[(size_t)s0 * 128 + c0];
        uint4 f1 = *(const uint4*)&feat1[(size_t)s1 * 128 + c0];
        uint4 f2 = *(const uint4*)&feat1[(size_t)s2 * 128 + c0];
        uint4 f3 = *(const uint4*)&feat1[(size_t)s3 * 128 + c0];
        uint4 f4 = *(const uint4*)&feat1[(size_t)s4 * 128 + c0];
        uint4 f5 = *(const uint4*)&feat1[(size_t)s5 * 128 + c0];
        uint4 f6 = *(const uint4*)&feat1[(size_t)s6 * 128 + c0];
        uint4 f7 = *(const uint4*)&feat1[(size_t)s7 * 128 + c0];
        float w0 = __expf(lrelu(e0 + er_d));
        float w1 = __expf(lrelu(e1 + er_d));
        float w2 = __expf(lrelu(e2 + er_d));
        float w3 = __expf(lrelu(e3 + er_d));
        float w4 = __expf(lrelu(e4 + er_d));
        float w5 = __expf(lrelu(e5 + er_d));
        float w6 = __expf(lrelu(e6 + er_d));
        float w7 = __expf(lrelu(e7 + er_d));
        ACC_EDGE(w0, f0) ACC_EDGE(w1, f1) ACC_EDGE(w2, f2) ACC_EDGE(w3, f3)
        ACC_EDGE(w4, f4) ACC_EDGE(w5, f5) ACC_EDGE(w6, f6) ACC_EDGE(w7, f7)
        i += 8;
    }
    if (i + 4 <= end) {
        int s0 = csr_src[i],     s1 = csr_src[i + 1];
        int s2 = csr_src[i + 2], s3 = csr_src[i + 3];
        float e0 = el1[s0 * 8 + hh], e1 = el1[s1 * 8 + hh];
        float e2 = el1[s2 * 8 + hh], e3 = el1[s3 * 8 + hh];
        uint4 f0 = *(const uint4*)&feat1[(size_t)s0 * 128 + c0];
        uint4 f1 = *(const uint4*)&feat1[(size_t)s1 * 128 + c0];
        uint4 f2 = *(const uint4*)&feat1[(size_t)s2 * 128 + c0];
        uint4 f3 = *(const uint4*)&feat1[(size_t)s3 * 128 + c0];
        float w0 = __expf(lrelu(e0 + er_d));
        float w1 = __expf(lrelu(e1 + er_d));
        float w2 = __expf(lrelu(e2 + er_d));
        float w3 = __expf(lrelu(e3 + er_d));
        ACC_EDGE(w0, f0) ACC_EDGE(w1, f1) ACC_EDGE(w2, f2) ACC_EDGE(w3, f3)
        i += 4;
    }
    while (i < end) {                                // <= 3 tail edges
        int s0 = csr_src[i];
        float w0 = __expf(lrelu(el1[s0 * 8 + hh] + er_d));
        uint4 f0 = *(const uint4*)&feat1[(size_t)s0 * 128 + c0];
        ACC_EDGE(w0, f0)
        ++i;
    }
    float inv = 1.f / fmaxf(wsum, 1e-9f);
    int isf32 = *flag;
    float v0 = a0 * inv + loadf(b1, c0 + 0, isf32);
    float v1 = a1 * inv + loadf(b1, c0 + 1, isf32);
    float v2 = a2 * inv + loadf(b1, c0 + 2, isf32);
    float v3 = a3 * inv + loadf(b1, c0 + 3, isf32);
    float v4 = a4 * inv + loadf(b1, c0 + 4, isf32);
    float v5 = a5 * inv + loadf(b1, c0 + 5, isf32);
    float v6 = a6 * inv + loadf(b1, c0 + 6, isf32);
    float v7 = a7 * inv + loadf(b1, c0 + 7, isf32);
    v0 = v0 > 0.f ? v0 : expm1f(v0);
    v1 = v1 > 0.f ? v1 : expm1f(v1);
    v2 = v2 > 0.f ? v2 : expm1f(v2);
    v3 = v3 > 0.f ? v3 : expm1f(v3);
    v4 = v4 > 0.f ? v4 : expm1f(v4);
    v5 = v5 > 0.f ? v5 : expm1f(v5);
    v6 = v6 > 0.f ? v6 : expm1f(v6);
    v7 = v7 > 0.f ? v7 : expm1f(v7);
    uint4 o;
    o.x = (u32)f2bf(v0) | ((u32)f2bf(v1) << 16);
    o.y = (u32)f2bf(v2) | ((u32)f2bf(v3) << 16);
    o.z = (u32)f2bf(v4) | ((u32)f2bf(v5) << 16);
    o.w = (u32)f2bf(v6) | ((u32)f2bf(v7) << 16);
    *(uint4*)&outp[(size_t)d * ostride + ql * 8] = o;
}

// ---- layer-2 aggregation: 8 nodes/wave, 8 lanes/node, 8 cols/lane;
//      feat2 lives in hC cols 64-127 slots (stride 128); 8-edge unroll ----
__global__ __launch_bounds__(256) void k_agg2c(
    const int* __restrict__ ptr, const int* __restrict__ csr_src,
    const float* __restrict__ el2, const float* __restrict__ er2,
    const u16* __restrict__ feat2,
    const void* __restrict__ b2, const int* __restrict__ flag,
    void* __restrict__ out)
{
    const int wv = threadIdx.x >> 6, lane = threadIdx.x & 63;
    const int g = lane >> 3, ql = lane & 7;
    const int d = blockIdx.x * 32 + wv * 8 + g;
    const int c0 = ql * 8;

    float er_d = er2[d];
    int start = d ? ptr[d - 1] : 0;
    int end   = ptr[d];

    float a0 = 0.f, a1 = 0.f, a2 = 0.f, a3 = 0.f;
    float a4 = 0.f, a5 = 0.f, a6 = 0.f, a7 = 0.f, wsum = 0.f;
    int i = start;
    while (i + 8 <= end) {
        int s0 = csr_src[i],     s1 = csr_src[i + 1];
        int s2 = csr_src[i + 2], s3 = csr_src[i + 3];
        int s4 = csr_src[i + 4], s5 = csr_src[i + 5];
        int s6 = csr_src[i + 6], s7 = csr_src[i + 7];
        float e0 = el2[s0], e1 = el2[s1], e2 = el2[s2], e3 = el2[s3];
        float e4 = el2[s4], e5 = el2[s5], e6 = el2[s6], e7 = el2[s7];
        uint4 f0 = *(const uint4*)&feat2[(size_t)s0 * 128 + c0];
        uint4 f1 = *(const uint4*)&feat2[(size_t)s1 * 128 + c0];
        uint4 f2 = *(const uint4*)&feat2[(size_t)s2 * 128 + c0];
        uint4 f3 = *(const uint4*)&feat2[(size_t)s3 * 128 + c0];
        uint4 f4 = *(const uint4*)&feat2[(size_t)s4 * 128 + c0];
        uint4 f5 = *(const uint4*)&feat2[(size_t)s5 * 128 + c0];
        uint4 f6 = *(const uint4*)&feat2[(size_t)s6 * 128 + c0];
        uint4 f7 = *(const uint4*)&feat2[(size_t)s7 * 128 + c0];
        float w0 = __expf(lrelu(e0 + er_d));
        float w1 = __expf(lrelu(e1 + er_d));
        float w2 = __expf(lrelu(e2 + er_d));
        float w3 = __expf(lrelu(e3 + er_d));
        float w4 = __expf(lrelu(e4 + er_d));
        float w5 = __expf(lrelu(e5 + er_d));
        float w6 = __expf(lrelu(e6 + er_d));
        float w7 = __expf(lrelu(e7 + er_d));
        ACC_EDGE(w0, f0) ACC_EDGE(w1, f1) ACC_EDGE(w2, f2) ACC_EDGE(w3, f3)
        ACC_EDGE(w4, f4) ACC_EDGE(w5, f5) ACC_EDGE(w6, f6) ACC_EDGE(w7, f7)
        i += 8;
    }
    if (i + 4 <= end) {
        int s0 = csr_src[i],     s1 = csr_src[i + 1];
        int s2 = csr_src[i + 2], s3 = csr_src[i + 3];
        float e0 = el2[s0], e1 = el2[s1], e2 = el2[s2], e3 = el2[s3];
        uint4 f0 = *(const uint4*)&feat2[(size_t)s0 * 128 + c0];
        uint4 f1 = *(const uint4*)&feat2[(size_t)s1 * 128 + c0];
        uint4 f2 = *(const uint4*)&feat2[(size_t)s2 * 128 + c0];
        uint4 f3 = *(const uint4*)&feat2[(size_t)s3 * 128 + c0];
        float w0 = __expf(lrelu(e0 + er_d));
        float w1 = __expf(lrelu(e1 + er_d));
        float w2 = __expf(lrelu(e2 + er_d));
        float w3 = __expf(lrelu(e3 + er_d));
        ACC_EDGE(w0, f0) ACC_EDGE(w1, f1) ACC_EDGE(w2, f2) ACC_EDGE(w3, f3)
        i += 4;
    }
    while (i < end) {
        int s0 = csr_src[i];
        float w0 = __expf(lrelu(el2[s0] + er_d));
        uint4 f0 = *(const uint4*)&feat2[(size_t)s0 * 128 + c0];
        ACC_EDGE(w0, f0)
        ++i;
    }
    float inv = 1.f / fmaxf(wsum, 1e-9f);
    int isf32 = *flag;
    float v0 = a0 * inv + loadf(b2, c0 + 0, isf32);
    float v1 = a1 * inv + loadf(b2, c0 + 1, isf32);
    float v2 = a2 * inv + loadf(b2, c0 + 2, isf32);
    float v3 = a3 * inv + loadf(b2, c0 + 3, isf32);
    float v4 = a4 * inv + loadf(b2, c0 + 4, isf32);
    float v5 = a5 * inv + loadf(b2, c0 + 5, isf32);
    float v6 = a6 * inv + loadf(b2, c0 + 6, isf32);
    float v7 = a7 * inv + loadf(b2, c0 + 7, isf32);
    size_t idx = (size_t)d * 64 + c0;
    if (isf32) {
        float4 oa; oa.x = v0; oa.y = v1; oa.z = v2; oa.w = v3;
        float4 ob; ob.x = v4; ob.y = v5; ob.z = v6; ob.w = v7;
        *(float4*)&((float*)out)[idx]     = oa;
        *(float4*)&((float*)out)[idx + 4] = ob;
    } else {
        uint4 o;
        o.x = (u32)f2bf(v0) | ((u32)f2bf(v1) << 16);
        o.y = (u32)f2bf(v2) | ((u32)f2bf(v3) << 16);
        o.z = (u32)f2bf(v4) | ((u32)f2bf(v5) << 16);
        o.w = (u32)f2bf(v6) | ((u32)f2bf(v7) << 16);
        *(uint4*)&((u16*)out)[idx] = o;
    }
}

// ---------------- launch ----------------
extern "C" void kernel_launch(void* const* d_in, const int* in_sizes, int n_in,
                              void* d_out, int out_size, void* d_ws, size_t ws_size,
                              hipStream_t stream)
{
    static const int exp_sizes[11] = {12800000, 1600000, 1600000, 16384, 128, 128, 128, 8192, 64, 64, 64};
    float code = 0.f;
    if (n_in != 11) code = 9000.f;
    else {
        for (int i = 0; i < 11; ++i)
            if (in_sizes[i] != exp_sizes[i]) { code = 3000.f + 100.f * i; break; }
    }
    if (code == 0.f && out_size != 6400000) code = 7777.f;
    if (code == 0.f && ws_size < 46100000)  code = (float)(ws_size >> 20);
    if (code != 0.f) {
        k_beacon<<<(out_size + 255) / 256, 256, 0, stream>>>((u16*)d_out, out_size, code);
        return;
    }

    const void* x   = d_in[0];
    const int* src  = (const int*)d_in[1];
    const int* dst  = (const int*)d_in[2];
    const void* W1  = d_in[3];
    const void* al1 = d_in[4];
    const void* ar1 = d_in[5];
    const void* b1  = d_in[6];
    const void* W2  = d_in[7];
    const void* al2 = d_in[8];
    const void* ar2 = d_in[9];
    const void* b2  = d_in[10];

    char* base = (char*)d_ws;
    int*   flag  = (int*)   base;                    // +0
    u16*   hC    = (u16*)  (base + 256);             // 25.6 MB: feat1 -> h-hi/feat2
    u16*   T     = (u16*)  (base + 25600256);        // 12.8 MB: pairs, then h-lo
    u32*   pair  = (u32*)  (base + 25600256);        // overlays T during CSR build (6.4 MB)
    int*   csr   = (int*)  (base + 38400256);        //  6.4 MB
    int*   ptr   = (int*)  (base + 44800256);        //  0.4 MB (row ends)
    int*   gcnt  = (int*)  (base + 44800256);        //  153 KB, overlays ptr (dead first)
    float* el2   = (float*)(base + 45200256);        //  0.4 MB
    float* er2   = (float*)(base + 45600256);        //  0.4 MB
    int*   total = (int*)  (base + 46000256);        //  392 B
    int*   bstart= (int*)  (base + 46002304);        //  396 B
    u16*   W1T   = (u16*)  (base + 46004352);        //  32 KB
    u16*   W2T   = (u16*)  (base + 46037120);        //  16 KB -> ends 46053504

    // el1/er1 scratch in d_out (6.4 MB <= 12.8 MB min), dead before final store
    float* el1 = (float*)d_out;
    float* er1 = el1 + 800000;

    u16* hLo   = T;            // h cols 0-63 (N x 64, stride 64)
    u16* hHi   = hC;           // h cols 64-127 in hC cols 0-63 slots (stride 128)
    u16* feat2 = hC + 64;      // feat2 in hC cols 64-127 slots (stride 128)

    k_detect<<<1, 256, 0, stream>>>((const u16*)x, flag);
    k_prep  <<<96, 256, 0, stream>>>(W1, W2, flag, W1T, W2T);

    k_gemm1m<<<1563, 256, 0, stream>>>(x, W1T, al1, ar1, flag, hC, el1, er1);

    // ---- CSR build: bucket counts -> scans -> partition -> per-bucket build ----
    k_cnt  <<<NB,  256, 0, stream>>>(dst, gcnt);
    k_scan1<<<NBK, 512, 0, stream>>>(gcnt, total);
    k_scan2<<<1,   128, 0, stream>>>(total, bstart);
    k_part <<<NB,  256, 0, stream>>>(src, dst, gcnt, bstart, pair);
    k_build<<<NBK, 256, 0, stream>>>(pair, bstart, ptr, csr);

    // ---- layer-1 aggregation: half-0 -> T; half-1 -> hC cols 0-63 (in place) ----
    k_agg1c<<<3125, 256, 0, stream>>>(ptr, csr, el1, er1, hC, b1, flag, hLo, 64, 0);
    k_agg1c<<<3125, 256, 0, stream>>>(ptr, csr, el1, er1, hC, b1, flag, hHi, 128, 64);

    k_gemm2m<<<1563, 256, 0, stream>>>(hLo, hHi, W2T, al2, ar2, flag, feat2, el2, er2);

    k_agg2c<<<3125, 256, 0, stream>>>(ptr, csr, el2, er2, feat2, b2, flag, d_out);
}

// Round 15
// 337.049 us; speedup vs baseline: 1.0437x; 1.0437x over previous
//
#include <hip/hip_runtime.h>
#include <hip/hip_bf16.h>

// GAT_52673478918844 — 2-layer GAT, N=100k, E=1.6M.
// CSR-gather + MFMA GEMMs + fully-bucketed CSR build (no global atomics)
// + 8-col/lane gather waves, 4-edge unroll, zero-copy h/feat2 overlays.
// (Round-11/13 configuration — measured best: 339.8/341.5 µs. Round-12's
//  NT/fusion and round-14's 8-edge unroll both regressed and are reverted.)
//
// ws layout (gate 46.1 MB):
//   +0        flag (int, padded to 256B)
//   +256      hC : N x 128 bf16 (25.6 MB)
//             phase 1: feat1 (all 128 cols)
//             phase 2: cols 0-63 slots = h-hi (written in-place by agg1 half-1)
//                      cols 64-127 slots = feat2 (written by gemm2)
//   +25.6M    T  : N x 64 bf16 (12.8 MB): pair_buf during CSR build, then h-lo
//   +38.4M    csr: int E — src ids sorted by dst                      6.4 MB
//   +44.8M    ptr: int N — row ends (gcnt overlays during build)      0.4 MB
//   +45.2M    el2, er2 (f32 N each)                                   0.8 MB
//   +46.0M    total[98], bstart[99] scratch                           ~4 KB
//   +46.004M  W1T bf16 128x128 (32 KB), W2T bf16 64x128 (16 KB)
// el1/er1 (f32 N*8 each) live in d_out until layer-1 agg done.

#define NN 100000
#define NE 1600000
#define NB 391          // ceil(NE/4096) edge blocks
#define NBK 98          // buckets = ceil(NN/1024), bucket = dst >> 10

typedef unsigned short u16;
typedef unsigned int   u32;
typedef __attribute__((ext_vector_type(4))) float f32x4;
typedef __attribute__((ext_vector_type(8))) short short8;   // 8 bf16 bits

__device__ __forceinline__ float bf2f(u16 u) { return __uint_as_float(((u32)u) << 16); }
__device__ __forceinline__ float bflo(u32 u) { return __uint_as_float(u << 16); }
__device__ __forceinline__ float bfhi(u32 u) { return __uint_as_float(u & 0xffff0000u); }
__device__ __forceinline__ u16 f2bf(float f) {
    u32 u = __float_as_uint(f);
    return (u16)((u + 0x7fffu + ((u >> 16) & 1u)) >> 16);   // RNE
}
__device__ __forceinline__ float lrelu(float v) { return v > 0.f ? v : 0.2f * v; }
__device__ __forceinline__ float loadf(const void* p, size_t i, int isf32) {
    return isf32 ? ((const float*)p)[i] : bf2f(((const u16*)p)[i]);
}

// ---- dtype autodetect ----
__global__ void k_detect(const u16* __restrict__ x, int* __restrict__ flag)
{
    __shared__ float s[256];
    int t = threadIdx.x;
    float a = 0.f;
    for (int i = t; i < 1024; i += 256) a += fminf(fabsf(bf2f(x[i])), 1e6f);
    s[t] = a;
    __syncthreads();
    if (t == 0) {
        float tot = 0.f;
        for (int i = 0; i < 256; ++i) tot += s[i];
        *flag = (tot * (1.f / 1024.f) > 100.f) ? 1 : 0;
    }
}

// ---- beacon ----
__global__ void k_beacon(u16* __restrict__ out, int n, float code)
{
    int tid = blockIdx.x * 256 + threadIdx.x;
    if (tid < n) out[tid] = f2bf(code);
}

// ---- weight transpose + bf16 convert: W1T[n][k], W2T[n][k] ----
__global__ __launch_bounds__(256) void k_prep(
    const void* __restrict__ W1, const void* __restrict__ W2,
    const int* __restrict__ flag, u16* __restrict__ W1T, u16* __restrict__ W2T)
{
    int i = blockIdx.x * 256 + threadIdx.x;
    int isf32 = *flag;
    if (i < 16384) {
        int k = i >> 7, n = i & 127;
        W1T[n * 128 + k] = isf32 ? f2bf(((const float*)W1)[i]) : ((const u16*)W1)[i];
    } else if (i < 24576) {
        int j = i - 16384;
        int k = j >> 6, n = j & 63;
        W2T[n * 128 + k] = isf32 ? f2bf(((const float*)W2)[j]) : ((const u16*)W2)[j];
    }
}

// ---- GEMM1 (MFMA): feat1 = x @ W1 -> hC (bf16) + el1/er1 (f32) ----
__global__ __launch_bounds__(256) void k_gemm1m(
    const void* __restrict__ x, const u16* __restrict__ W1T,
    const void* __restrict__ al1, const void* __restrict__ ar1,
    const int* __restrict__ flag,
    u16* __restrict__ hC, float* __restrict__ el1, float* __restrict__ er1)
{
    __shared__ __align__(16) char smem[52224];
    __shared__ float alS[128], arS[128];
    u16* xT = (u16*)smem;              // [64][136]
    u16* wT = (u16*)(smem + 17408);    // [128][136]
    float* fB = (float*)smem;          // [64][132] f32, epilogue reuse

    const int t  = threadIdx.x;
    const int r0 = blockIdx.x * 64;
    const int isf32 = *flag;

    if (t < 128) { alS[t] = loadf(al1, t, isf32); arS[t] = loadf(ar1, t, isf32); }

    {
        const uint4* wg = (const uint4*)W1T;
        #pragma unroll
        for (int it = 0; it < 8; ++it) {
            int idx = t + it * 256;
            int r = idx >> 4, k = (idx & 15) * 8;
            *(uint4*)&wT[r * 136 + k] = wg[idx];
        }
    }
    if (!isf32) {
        const u16* xg = (const u16*)x;
        #pragma unroll
        for (int it = 0; it < 4; ++it) {
            int idx = t + it * 256;
            int r = idx >> 4, k = (idx & 15) * 8;
            int rr = r0 + r; if (rr >= NN) rr = NN - 1;
            *(uint4*)&xT[r * 136 + k] = *(const uint4*)&xg[(size_t)rr * 128 + k];
        }
    } else {
        const float* xg = (const float*)x;
        #pragma unroll
        for (int it = 0; it < 8; ++it) {
            int idx = t + it * 256;
            int r = idx >> 5, k = (idx & 31) * 4;
            int rr = r0 + r; if (rr >= NN) rr = NN - 1;
            float4 v = *(const float4*)&xg[(size_t)rr * 128 + k];
            ushort4 o; o.x = f2bf(v.x); o.y = f2bf(v.y); o.z = f2bf(v.z); o.w = f2bf(v.w);
            *(ushort4*)&xT[r * 136 + k] = o;
        }
    }
    __syncthreads();

    const int w = t >> 6, lane = t & 63;
    const int lm = lane & 15, lk = (lane >> 4) * 8;
    const u16* aP = &xT[(w * 16 + lm) * 136 + lk];
    const u16* bP = &wT[lm * 136 + lk];

    f32x4 acc[8];
    #pragma unroll
    for (int i = 0; i < 8; ++i) acc[i] = (f32x4){0.f, 0.f, 0.f, 0.f};

    #pragma unroll
    for (int ks = 0; ks < 4; ++ks) {
        short8 a = *(const short8*)(aP + ks * 32);
        #pragma unroll
        for (int ct = 0; ct < 8; ++ct) {
            short8 b = *(const short8*)(bP + ct * 16 * 136 + ks * 32);
            acc[ct] = __builtin_amdgcn_mfma_f32_16x16x32_bf16(a, b, acc[ct], 0, 0, 0);
        }
    }
    __syncthreads();

    {
        int rbase = w * 16 + (lane >> 4) * 4;
        #pragma unroll
        for (int ct = 0; ct < 8; ++ct) {
            #pragma unroll
            for (int r = 0; r < 4; ++r)
                fB[(rbase + r) * 132 + ct * 16 + lm] = acc[ct][r];
        }
    }
    __syncthreads();

    #pragma unroll
    for (int it = 0; it < 16; ++it) {
        int idx = t + it * 256;                    // < 4096
        int r = idx >> 6, c2 = (idx & 63) * 2;
        int rr = r0 + r;
        if (rr < NN) {
            u32 pk = (u32)f2bf(fB[r * 132 + c2]) | ((u32)f2bf(fB[r * 132 + c2 + 1]) << 16);
            *(u32*)&hC[(size_t)rr * 128 + c2] = pk;
        }
    }
    #pragma unroll
    for (int p = 0; p < 2; ++p) {
        int task = t + p * 256;                    // < 512
        int r = task >> 3, hh = task & 7;
        float el = 0.f, er = 0.f;
        #pragma unroll
        for (int dd = 0; dd < 16; ++dd) {
            float f = fB[r * 132 + hh * 16 + dd];
            el += f * alS[hh * 16 + dd];
            er += f * arS[hh * 16 + dd];
        }
        int rr = r0 + r;
        if (rr < NN) { el1[rr * 8 + hh] = el; er1[rr * 8 + hh] = er; }
    }
}

// ---- GEMM2 (MFMA): feat2 = h @ W2 -> feat2 (hC cols 64-127 slots) + el2/er2 ----
// h read from T (cols 0-63, stride 64) and hC cols 0-63 slots (cols 64-127, stride 128)
__global__ __launch_bounds__(256) void k_gemm2m(
    const u16* __restrict__ hT, const u16* __restrict__ hHi,
    const u16* __restrict__ W2T,
    const void* __restrict__ al2, const void* __restrict__ ar2,
    const int* __restrict__ flag,
    u16* __restrict__ feat2, float* __restrict__ el2, float* __restrict__ er2)
{
    __shared__ __align__(16) char smem[34816];
    __shared__ float alS[64], arS[64];
    u16* xT = (u16*)smem;              // [64][136]
    u16* wT = (u16*)(smem + 17408);    // [64][136]
    float* fB = (float*)smem;          // [64][68] f32, epilogue reuse

    const int t  = threadIdx.x;
    const int r0 = blockIdx.x * 64;
    const int isf32 = *flag;

    if (t < 64) { alS[t] = loadf(al2, t, isf32); arS[t] = loadf(ar2, t, isf32); }

    {
        const uint4* wg = (const uint4*)W2T;       // 64*128 = 1024 uint4
        #pragma unroll
        for (int it = 0; it < 4; ++it) {
            int idx = t + it * 256;
            int r = idx >> 4, k = (idx & 15) * 8;
            *(uint4*)&wT[r * 136 + k] = wg[idx];
        }
    }
    #pragma unroll
    for (int it = 0; it < 4; ++it) {
        int idx = t + it * 256;
        int r = idx >> 4, j = idx & 15;            // 16-B chunk = 8 cols
        int rr = r0 + r; if (rr >= NN) rr = NN - 1;
        const u16* sp = (j < 8) ? &hT[(size_t)rr * 64 + j * 8]
                                : &hHi[(size_t)rr * 128 + (j - 8) * 8];
        *(uint4*)&xT[r * 136 + j * 8] = *(const uint4*)sp;
    }
    __syncthreads();

    const int w = t >> 6, lane = t & 63;
    const int lm = lane & 15, lk = (lane >> 4) * 8;
    const u16* aP = &xT[(w * 16 + lm) * 136 + lk];
    const u16* bP = &wT[lm * 136 + lk];

    f32x4 acc[4];
    #pragma unroll
    for (int i = 0; i < 4; ++i) acc[i] = (f32x4){0.f, 0.f, 0.f, 0.f};

    #pragma unroll
    for (int ks = 0; ks < 4; ++ks) {
        short8 a = *(const short8*)(aP + ks * 32);
        #pragma unroll
        for (int ct = 0; ct < 4; ++ct) {
            short8 b = *(const short8*)(bP + ct * 16 * 136 + ks * 32);
            acc[ct] = __builtin_amdgcn_mfma_f32_16x16x32_bf16(a, b, acc[ct], 0, 0, 0);
        }
    }
    __syncthreads();

    {
        int rbase = w * 16 + (lane >> 4) * 4;
        #pragma unroll
        for (int ct = 0; ct < 4; ++ct) {
            #pragma unroll
            for (int r = 0; r < 4; ++r)
                fB[(rbase + r) * 68 + ct * 16 + lm] = acc[ct][r];
        }
    }
    __syncthreads();

    // feat2 store into hC cols 64-127 slots: stride 128, cols 0-63 local
    #pragma unroll
    for (int it = 0; it < 8; ++it) {
        int idx = t + it * 256;                    // < 2048
        int r = idx >> 5, c2 = (idx & 31) * 2;
        int rr = r0 + r;
        if (rr < NN) {
            u32 pk = (u32)f2bf(fB[r * 68 + c2]) | ((u32)f2bf(fB[r * 68 + c2 + 1]) << 16);
            *(u32*)&feat2[(size_t)rr * 128 + c2] = pk;
        }
    }
    {
        int r = t >> 2, q = t & 3;
        float el = 0.f, er = 0.f;
        #pragma unroll
        for (int dd = 0; dd < 16; ++dd) {
            float f = fB[r * 68 + q * 16 + dd];
            el += f * alS[q * 16 + dd];
            er += f * arS[q * 16 + dd];
        }
        el += __shfl_xor(el, 1); el += __shfl_xor(el, 2);
        er += __shfl_xor(er, 1); er += __shfl_xor(er, 2);
        int rr = r0 + r;
        if (q == 0 && rr < NN) { el2[rr] = el; er2[rr] = er; }
    }
}

// ---- CSR build (fully bucketed, no global atomics, packed u32 pairs) ----
// pack = (local_dst << 17) | src   (src < 2^17, local_dst < 1024)

__global__ __launch_bounds__(256) void k_cnt(
    const int* __restrict__ dst, int* __restrict__ gcnt)
{
    __shared__ int cnt[NBK];
    const int t = threadIdx.x;
    if (t < NBK) cnt[t] = 0;
    __syncthreads();
    const int e0 = blockIdx.x * 4096 + t;
    #pragma unroll
    for (int i = 0; i < 16; ++i) {
        int e = e0 + i * 256;
        if (e < NE) atomicAdd(&cnt[dst[e] >> 10], 1);
    }
    __syncthreads();
    if (t < NBK) gcnt[blockIdx.x * NBK + t] = cnt[t];
}

__global__ __launch_bounds__(512) void k_scan1(
    int* __restrict__ gcnt, int* __restrict__ total)
{
    __shared__ int s[512];
    const int t = threadIdx.x, k = blockIdx.x;
    int c = (t < NB) ? gcnt[t * NBK + k] : 0;
    s[t] = c; __syncthreads();
    for (int off = 1; off < 512; off <<= 1) {
        int v = (t >= off) ? s[t - off] : 0;
        __syncthreads();
        s[t] += v;
        __syncthreads();
    }
    if (t < NB) gcnt[t * NBK + k] = s[t] - c;
    if (t == NB - 1) total[k] = s[t];
}

__global__ __launch_bounds__(128) void k_scan2(
    const int* __restrict__ total, int* __restrict__ bstart)
{
    __shared__ int s[128];
    const int t = threadIdx.x;
    int c = (t < NBK) ? total[t] : 0;
    s[t] = c; __syncthreads();
    for (int off = 1; off < 128; off <<= 1) {
        int v = (t >= off) ? s[t - off] : 0;
        __syncthreads();
        s[t] += v;
        __syncthreads();
    }
    if (t < NBK) bstart[t] = s[t] - c;
    if (t == NBK - 1) bstart[NBK] = s[t];
}

__global__ __launch_bounds__(256) void k_part(
    const int* __restrict__ src, const int* __restrict__ dst,
    const int* __restrict__ gcnt, const int* __restrict__ bstart,
    u32* __restrict__ pair)
{
    __shared__ int cnt[NBK];
    __shared__ int gb[NBK];
    const int t = threadIdx.x;
    const int e0 = blockIdx.x * 4096 + t;

    if (t < NBK) cnt[t] = 0;
    __syncthreads();

    int sv[16], dv[16], rk[16];
    #pragma unroll
    for (int i = 0; i < 16; ++i) {
        int e = e0 + i * 256;
        if (e < NE) {
            sv[i] = src[e];
            dv[i] = dst[e];
            rk[i] = atomicAdd(&cnt[dv[i] >> 10], 1);
        }
    }
    __syncthreads();
    if (t < NBK) gb[t] = bstart[t] + gcnt[blockIdx.x * NBK + t];
    __syncthreads();

    #pragma unroll
    for (int i = 0; i < 16; ++i) {
        int e = e0 + i * 256;
        if (e < NE) {
            u32 p = ((u32)(dv[i] & 1023) << 17) | (u32)sv[i];
            pair[gb[dv[i] >> 10] + rk[i]] = p;
        }
    }
}

__global__ __launch_bounds__(256) void k_build(
    const u32* __restrict__ pair, const int* __restrict__ bstart,
    int* __restrict__ ptr, int* __restrict__ csr_src)
{
    __shared__ int cur[1024];
    __shared__ int part[256];
    const int t = threadIdx.x;
    const int b = blockIdx.x;
    const int r0 = b << 10;
    const int nloc = min(1024, NN - r0);
    const int bs = bstart[b], be = bstart[b + 1];

    for (int i = t; i < 1024; i += 256) cur[i] = 0;
    __syncthreads();

    for (int e = bs + t; e < be; e += 256)
        atomicAdd(&cur[pair[e] >> 17], 1);
    __syncthreads();

    int t4 = t * 4;
    int c0 = cur[t4], c1 = cur[t4 + 1], c2 = cur[t4 + 2], c3 = cur[t4 + 3];
    int sum = c0 + c1 + c2 + c3;
    part[t] = sum; __syncthreads();
    for (int off = 1; off < 256; off <<= 1) {
        int v = (t >= off) ? part[t - off] : 0;
        __syncthreads();
        part[t] += v;
        __syncthreads();
    }
    int basep = bs + part[t] - sum;
    cur[t4]     = basep;
    cur[t4 + 1] = basep + c0;
    cur[t4 + 2] = basep + c0 + c1;
    cur[t4 + 3] = basep + c0 + c1 + c2;
    __syncthreads();

    for (int e = bs + t; e < be; e += 256) {
        u32 p = pair[e];
        int pos = atomicAdd(&cur[p >> 17], 1);
        csr_src[pos] = (int)(p & 0x1FFFFu);
    }
    __syncthreads();

    for (int i = t; i < nloc; i += 256) ptr[r0 + i] = cur[i];   // row ends
}

// ---- layer-1 aggregation: 8 nodes/wave, 8 lanes/node, 8 cols/lane,
//      4-edge unrolled main loop; output stride parameterized so half-1
//      writes straight into hC's dead cols-0-63 slots (no copy kernel) ----
__global__ __launch_bounds__(256) void k_agg1c(
    const int* __restrict__ ptr, const int* __restrict__ csr_src,
    const float* __restrict__ el1, const float* __restrict__ er1,
    const u16* __restrict__ feat1,
    const void* __restrict__ b1, const int* __restrict__ flag,
    u16* __restrict__ outp, int ostride, int cb)
{
    const int wv = threadIdx.x >> 6, lane = threadIdx.x & 63;
    const int g = lane >> 3, ql = lane & 7;
    const int d = blockIdx.x * 32 + wv * 8 + g;      // 3125 * 32 = NN exactly
    const int c0 = cb + ql * 8;                      // 8 cols: c0..c0+7
    const int hh = c0 >> 4;

    float er_d = er1[d * 8 + hh];
    int start = d ? ptr[d - 1] : 0;
    int end   = ptr[d];

    float a0 = 0.f, a1 = 0.f, a2 = 0.f, a3 = 0.f;
    float a4 = 0.f, a5 = 0.f, a6 = 0.f, a7 = 0.f, wsum = 0.f;
    int i = start;
    while (i + 4 <= end) {
        int s0 = csr_src[i], s1 = csr_src[i + 1];
        int s2 = csr_src[i + 2], s3 = csr_src[i + 3];
        float e0 = el1[s0 * 8 + hh], e1 = el1[s1 * 8 + hh];
        float e2 = el1[s2 * 8 + hh], e3 = el1[s3 * 8 + hh];
        uint4 f0 = *(const uint4*)&feat1[(size_t)s0 * 128 + c0];
        uint4 f1 = *(const uint4*)&feat1[(size_t)s1 * 128 + c0];
        uint4 f2 = *(const uint4*)&feat1[(size_t)s2 * 128 + c0];
        uint4 f3 = *(const uint4*)&feat1[(size_t)s3 * 128 + c0];
        float w0 = __expf(lrelu(e0 + er_d));
        float w1 = __expf(lrelu(e1 + er_d));
        float w2 = __expf(lrelu(e2 + er_d));
        float w3 = __expf(lrelu(e3 + er_d));
        a0 += w0 * bflo(f0.x); a1 += w0 * bfhi(f0.x);
        a2 += w0 * bflo(f0.y); a3 += w0 * bfhi(f0.y);
        a4 += w0 * bflo(f0.z); a5 += w0 * bfhi(f0.z);
        a6 += w0 * bflo(f0.w); a7 += w0 * bfhi(f0.w);
        wsum += w0;
        a0 += w1 * bflo(f1.x); a1 += w1 * bfhi(f1.x);
        a2 += w1 * bflo(f1.y); a3 += w1 * bfhi(f1.y);
        a4 += w1 * bflo(f1.z); a5 += w1 * bfhi(f1.z);
        a6 += w1 * bflo(f1.w); a7 += w1 * bfhi(f1.w);
        wsum += w1;
        a0 += w2 * bflo(f2.x); a1 += w2 * bfhi(f2.x);
        a2 += w2 * bflo(f2.y); a3 += w2 * bfhi(f2.y);
        a4 += w2 * bflo(f2.z); a5 += w2 * bfhi(f2.z);
        a6 += w2 * bflo(f2.w); a7 += w2 * bfhi(f2.w);
        wsum += w2;
        a0 += w3 * bflo(f3.x); a1 += w3 * bfhi(f3.x);
        a2 += w3 * bflo(f3.y); a3 += w3 * bfhi(f3.y);
        a4 += w3 * bflo(f3.z); a5 += w3 * bfhi(f3.z);
        a6 += w3 * bflo(f3.w); a7 += w3 * bfhi(f3.w);
        wsum += w3;
        i += 4;
    }
    while (i < end) {                                // <= 3 tail edges
        int s0 = csr_src[i];
        float w0 = __expf(lrelu(el1[s0 * 8 + hh] + er_d));
        uint4 f0 = *(const uint4*)&feat1[(size_t)s0 * 128 + c0];
        a0 += w0 * bflo(f0.x); a1 += w0 * bfhi(f0.x);
        a2 += w0 * bflo(f0.y); a3 += w0 * bfhi(f0.y);
        a4 += w0 * bflo(f0.z); a5 += w0 * bfhi(f0.z);
        a6 += w0 * bflo(f0.w); a7 += w0 * bfhi(f0.w);
        wsum += w0;
        ++i;
    }
    float inv = 1.f / fmaxf(wsum, 1e-9f);
    int isf32 = *flag;
    float v0 = a0 * inv + loadf(b1, c0 + 0, isf32);
    float v1 = a1 * inv + loadf(b1, c0 + 1, isf32);
    float v2 = a2 * inv + loadf(b1, c0 + 2, isf32);
    float v3 = a3 * inv + loadf(b1, c0 + 3, isf32);
    float v4 = a4 * inv + loadf(b1, c0 + 4, isf32);
    float v5 = a5 * inv + loadf(b1, c0 + 5, isf32);
    float v6 = a6 * inv + loadf(b1, c0 + 6, isf32);
    float v7 = a7 * inv + loadf(b1, c0 + 7, isf32);
    v0 = v0 > 0.f ? v0 : expm1f(v0);
    v1 = v1 > 0.f ? v1 : expm1f(v1);
    v2 = v2 > 0.f ? v2 : expm1f(v2);
    v3 = v3 > 0.f ? v3 : expm1f(v3);
    v4 = v4 > 0.f ? v4 : expm1f(v4);
    v5 = v5 > 0.f ? v5 : expm1f(v5);
    v6 = v6 > 0.f ? v6 : expm1f(v6);
    v7 = v7 > 0.f ? v7 : expm1f(v7);
    uint4 o;
    o.x = (u32)f2bf(v0) | ((u32)f2bf(v1) << 16);
    o.y = (u32)f2bf(v2) | ((u32)f2bf(v3) << 16);
    o.z = (u32)f2bf(v4) | ((u32)f2bf(v5) << 16);
    o.w = (u32)f2bf(v6) | ((u32)f2bf(v7) << 16);
    *(uint4*)&outp[(size_t)d * ostride + ql * 8] = o;
}

// ---- layer-2 aggregation: 8 nodes/wave, 8 lanes/node, 8 cols/lane;
//      feat2 lives in hC cols 64-127 slots (stride 128) ----
__global__ __launch_bounds__(256) void k_agg2c(
    const int* __restrict__ ptr, const int* __restrict__ csr_src,
    const float* __restrict__ el2, const float* __restrict__ er2,
    const u16* __restrict__ feat2,
    const void* __restrict__ b2, const int* __restrict__ flag,
    void* __restrict__ out)
{
    const int wv = threadIdx.x >> 6, lane = threadIdx.x & 63;
    const int g = lane >> 3, ql = lane & 7;
    const int d = blockIdx.x * 32 + wv * 8 + g;
    const int c0 = ql * 8;

    float er_d = er2[d];
    int start = d ? ptr[d - 1] : 0;
    int end   = ptr[d];

    float a0 = 0.f, a1 = 0.f, a2 = 0.f, a3 = 0.f;
    float a4 = 0.f, a5 = 0.f, a6 = 0.f, a7 = 0.f, wsum = 0.f;
    int i = start;
    while (i + 4 <= end) {
        int s0 = csr_src[i], s1 = csr_src[i + 1];
        int s2 = csr_src[i + 2], s3 = csr_src[i + 3];
        float e0 = el2[s0], e1 = el2[s1], e2 = el2[s2], e3 = el2[s3];
        uint4 f0 = *(const uint4*)&feat2[(size_t)s0 * 128 + c0];
        uint4 f1 = *(const uint4*)&feat2[(size_t)s1 * 128 + c0];
        uint4 f2 = *(const uint4*)&feat2[(size_t)s2 * 128 + c0];
        uint4 f3 = *(const uint4*)&feat2[(size_t)s3 * 128 + c0];
        float w0 = __expf(lrelu(e0 + er_d));
        float w1 = __expf(lrelu(e1 + er_d));
        float w2 = __expf(lrelu(e2 + er_d));
        float w3 = __expf(lrelu(e3 + er_d));
        a0 += w0 * bflo(f0.x); a1 += w0 * bfhi(f0.x);
        a2 += w0 * bflo(f0.y); a3 += w0 * bfhi(f0.y);
        a4 += w0 * bflo(f0.z); a5 += w0 * bfhi(f0.z);
        a6 += w0 * bflo(f0.w); a7 += w0 * bfhi(f0.w);
        wsum += w0;
        a0 += w1 * bflo(f1.x); a1 += w1 * bfhi(f1.x);
        a2 += w1 * bflo(f1.y); a3 += w1 * bfhi(f1.y);
        a4 += w1 * bflo(f1.z); a5 += w1 * bfhi(f1.z);
        a6 += w1 * bflo(f1.w); a7 += w1 * bfhi(f1.w);
        wsum += w1;
        a0 += w2 * bflo(f2.x); a1 += w2 * bfhi(f2.x);
        a2 += w2 * bflo(f2.y); a3 += w2 * bfhi(f2.y);
        a4 += w2 * bflo(f2.z); a5 += w2 * bfhi(f2.z);
        a6 += w2 * bflo(f2.w); a7 += w2 * bfhi(f2.w);
        wsum += w2;
        a0 += w3 * bflo(f3.x); a1 += w3 * bfhi(f3.x);
        a2 += w3 * bflo(f3.y); a3 += w3 * bfhi(f3.y);
        a4 += w3 * bflo(f3.z); a5 += w3 * bfhi(f3.z);
        a6 += w3 * bflo(f3.w); a7 += w3 * bfhi(f3.w);
        wsum += w3;
        i += 4;
    }
    while (i < end) {
        int s0 = csr_src[i];
        float w0 = __expf(lrelu(el2[s0] + er_d));
        uint4 f0 = *(const uint4*)&feat2[(size_t)s0 * 128 + c0];
        a0 += w0 * bflo(f0.x); a1 += w0 * bfhi(f0.x);
        a2 += w0 * bflo(f0.y); a3 += w0 * bfhi(f0.y);
        a4 += w0 * bflo(f0.z); a5 += w0 * bfhi(f0.z);
        a6 += w0 * bflo(f0.w); a7 += w0 * bfhi(f0.w);
        wsum += w0;
        ++i;
    }
    float inv = 1.f / fmaxf(wsum, 1e-9f);
    int isf32 = *flag;
    float v0 = a0 * inv + loadf(b2, c0 + 0, isf32);
    float v1 = a1 * inv + loadf(b2, c0 + 1, isf32);
    float v2 = a2 * inv + loadf(b2, c0 + 2, isf32);
    float v3 = a3 * inv + loadf(b2, c0 + 3, isf32);
    float v4 = a4 * inv + loadf(b2, c0 + 4, isf32);
    float v5 = a5 * inv + loadf(b2, c0 + 5, isf32);
    float v6 = a6 * inv + loadf(b2, c0 + 6, isf32);
    float v7 = a7 * inv + loadf(b2, c0 + 7, isf32);
    size_t idx = (size_t)d * 64 + c0;
    if (isf32) {
        float4 oa; oa.x = v0; oa.y = v1; oa.z = v2; oa.w = v3;
        float4 ob; ob.x = v4; ob.y = v5; ob.z = v6; ob.w = v7;
        *(float4*)&((float*)out)[idx]     = oa;
        *(float4*)&((float*)out)[idx + 4] = ob;
    } else {
        uint4 o;
        o.x = (u32)f2bf(v0) | ((u32)f2bf(v1) << 16);
        o.y = (u32)f2bf(v2) | ((u32)f2bf(v3) << 16);
        o.z = (u32)f2bf(v4) | ((u32)f2bf(v5) << 16);
        o.w = (u32)f2bf(v6) | ((u32)f2bf(v7) << 16);
        *(uint4*)&((u16*)out)[idx] = o;
    }
}

// ---------------- launch ----------------
extern "C" void kernel_launch(void* const* d_in, const int* in_sizes, int n_in,
                              void* d_out, int out_size, void* d_ws, size_t ws_size,
                              hipStream_t stream)
{
    static const int exp_sizes[11] = {12800000, 1600000, 1600000, 16384, 128, 128, 128, 8192, 64, 64, 64};
    float code = 0.f;
    if (n_in != 11) code = 9000.f;
    else {
        for (int i = 0; i < 11; ++i)
            if (in_sizes[i] != exp_sizes[i]) { code = 3000.f + 100.f * i; break; }
    }
    if (code == 0.f && out_size != 6400000) code = 7777.f;
    if (code == 0.f && ws_size < 46100000)  code = (float)(ws_size >> 20);
    if (code != 0.f) {
        k_beacon<<<(out_size + 255) / 256, 256, 0, stream>>>((u16*)d_out, out_size, code);
        return;
    }

    const void* x   = d_in[0];
    const int* src  = (const int*)d_in[1];
    const int* dst  = (const int*)d_in[2];
    const void* W1  = d_in[3];
    const void* al1 = d_in[4];
    const void* ar1 = d_in[5];
    const void* b1  = d_in[6];
    const void* W2  = d_in[7];
    const void* al2 = d_in[8];
    const void* ar2 = d_in[9];
    const void* b2  = d_in[10];

    char* base = (char*)d_ws;
    int*   flag  = (int*)   base;                    // +0
    u16*   hC    = (u16*)  (base + 256);             // 25.6 MB: feat1 -> h-hi/feat2
    u16*   T     = (u16*)  (base + 25600256);        // 12.8 MB: pairs, then h-lo
    u32*   pair  = (u32*)  (base + 25600256);        // overlays T during CSR build (6.4 MB)
    int*   csr   = (int*)  (base + 38400256);        //  6.4 MB
    int*   ptr   = (int*)  (base + 44800256);        //  0.4 MB (row ends)
    int*   gcnt  = (int*)  (base + 44800256);        //  153 KB, overlays ptr (dead first)
    float* el2   = (float*)(base + 45200256);        //  0.4 MB
    float* er2   = (float*)(base + 45600256);        //  0.4 MB
    int*   total = (int*)  (base + 46000256);        //  392 B
    int*   bstart= (int*)  (base + 46002304);        //  396 B
    u16*   W1T   = (u16*)  (base + 46004352);        //  32 KB
    u16*   W2T   = (u16*)  (base + 46037120);        //  16 KB -> ends 46053504

    // el1/er1 scratch in d_out (6.4 MB <= 12.8 MB min), dead before final store
    float* el1 = (float*)d_out;
    float* er1 = el1 + 800000;

    u16* hLo   = T;            // h cols 0-63 (N x 64, stride 64)
    u16* hHi   = hC;           // h cols 64-127 in hC cols 0-63 slots (stride 128)
    u16* feat2 = hC + 64;      // feat2 in hC cols 64-127 slots (stride 128)

    k_detect<<<1, 256, 0, stream>>>((const u16*)x, flag);
    k_prep  <<<96, 256, 0, stream>>>(W1, W2, flag, W1T, W2T);

    k_gemm1m<<<1563, 256, 0, stream>>>(x, W1T, al1, ar1, flag, hC, el1, er1);

    // ---- CSR build: bucket counts -> scans -> partition -> per-bucket build ----
    k_cnt  <<<NB,  256, 0, stream>>>(dst, gcnt);
    k_scan1<<<NBK, 512, 0, stream>>>(gcnt, total);
    k_scan2<<<1,   128, 0, stream>>>(total, bstart);
    k_part <<<NB,  256, 0, stream>>>(src, dst, gcnt, bstart, pair);
    k_build<<<NBK, 256, 0, stream>>>(pair, bstart, ptr, csr);

    // ---- layer-1 aggregation: half-0 -> T; half-1 -> hC cols 0-63 (in place) ----
    k_agg1c<<<3125, 256, 0, stream>>>(ptr, csr, el1, er1, hC, b1, flag, hLo, 64, 0);
    k_agg1c<<<3125, 256, 0, stream>>>(ptr, csr, el1, er1, hC, b1, flag, hHi, 128, 64);

    k_gemm2m<<<1563, 256, 0, stream>>>(hLo, hHi, W2T, al2, ar2, flag, feat2, el2, er2);

    k_agg2c<<<3125, 256, 0, stream>>>(ptr, csr, el2, er2, feat2, b2, flag, d_out);
}